// Round 1
// baseline (288.229 us; speedup 1.0000x reference)
//
#include <hip/hip_runtime.h>

#define NT 4096          // time samples per column
#define NCOL 4096        // 512 traces * 8 channels
#define EPT 32           // elements per lane: a wave PAIR (128 lanes) sorts one column
#define BLOCK 512        // 8 waves: {pred,obs} x {col 0,1} x {wave-of-pair 0,1}
#define NBLOCKS 2048     // 4096 cols / 2 cols per block

__device__ __forceinline__ float b2f(int i) { return __builtin_bit_cast(float, i); }
__device__ __forceinline__ int   f2b(float f) { return __builtin_bit_cast(int, f); }

// Cross-lane fetch of partner lane^XM's value.
// XM 1,2,3 (quad_perm), 7 (row_half_mirror), 8 (row_ror:8), 15 (row_mirror): DPP,
// VALU pipe, zero DS traffic. XM 4,16,31: ds_swizzle. XM 32,63: ds_bpermute
// (ds_swizzle xor-mask is 5-bit, cannot cross the 32-lane halves).
template <int XM>
__device__ __forceinline__ float lx(float v) {
    const int i = f2b(v);
    int r;
    if constexpr (XM == 1)       r = __builtin_amdgcn_update_dpp(0, i, 0xB1,  0xF, 0xF, true);
    else if constexpr (XM == 2)  r = __builtin_amdgcn_update_dpp(0, i, 0x4E,  0xF, 0xF, true);
    else if constexpr (XM == 3)  r = __builtin_amdgcn_update_dpp(0, i, 0x1B,  0xF, 0xF, true);
    else if constexpr (XM == 7)  r = __builtin_amdgcn_update_dpp(0, i, 0x141, 0xF, 0xF, true);
    else if constexpr (XM == 8)  r = __builtin_amdgcn_update_dpp(0, i, 0x128, 0xF, 0xF, true);
    else if constexpr (XM == 15) r = __builtin_amdgcn_update_dpp(0, i, 0x140, 0xF, 0xF, true);
    else if constexpr (XM == 4)  r = __builtin_amdgcn_ds_swizzle(i, 0x101F);
    else if constexpr (XM == 16) r = __builtin_amdgcn_ds_swizzle(i, 0x401F);
    else if constexpr (XM == 31) r = __builtin_amdgcn_ds_swizzle(i, 0x7C1F);
    else {
        const int lane = (int)(threadIdx.x & 63);
        r = __builtin_amdgcn_ds_bpermute((lane ^ XM) << 2, i);
    }
    return b2f(r);
}

__device__ __forceinline__ void cemin(float& a, float& b) {
    const float lo = fminf(a, b);
    const float hi = fmaxf(a, b);
    a = lo; b = hi;
}
__device__ __forceinline__ float csel(float x, float y, bool keep_min) {
    return ((x < y) == keep_min) ? x : y;
}

// plain cross-lane stage, lane-xor M, same element index
template <int M>
__device__ __forceinline__ void plain_stage(float (&x)[EPT], int L) {
    const bool km = (L & M) == 0;
    #pragma unroll
    for (int e = 0; e < EPT; ++e) {
        const float y = lx<M>(x[e]);
        x[e] = csel(x[e], y, km);
    }
}

template <int M>
__device__ __forceinline__ void plains_down(float (&x)[EPT], int L) {
    plain_stage<M>(x, L);
    if constexpr (M > 1) plains_down<M / 2>(x, L);
}

// intra-thread plain stages j = 16..1, all ascending (normalized network)
__device__ __forceinline__ void tail16(float (&x)[EPT]) {
    #pragma unroll
    for (int j = 16; j >= 1; j >>= 1) {
        #pragma unroll
        for (int e = 0; e < EPT; ++e)
            if ((e & j) == 0) cemin(x[e], x[e | j]);
    }
}

// Normalized bitonic merge of size k = 32*K (K = 2..64), fully in-wave:
// reversal: partner lane L^(K-1), element mirror e<->31-e, keep-min if (L&K/2)==0;
// then plain lane-xor stages m=K/4..1; then intra-thread tail j=16..1.
template <int K>
__device__ __forceinline__ void cross_merge(float (&x)[EPT], int L) {
    const bool km = (L & (K >> 1)) == 0;
    #pragma unroll
    for (int e = 0; e < EPT / 2; ++e) {
        const float ylo = lx<K - 1>(x[EPT - 1 - e]);   // partner's mirrored element
        const float yhi = lx<K - 1>(x[e]);
        x[e]           = csel(x[e], ylo, km);
        x[EPT - 1 - e] = csel(x[EPT - 1 - e], yhi, km);
    }
    if constexpr (K >= 4) plains_down<K / 4>(x, L);
    tail16(x);
}

// LDS (one union, phases are sequential):
//   staging transpose: 2 halves x 2 cols x 2048 words            = 8192 words
//   k=4096 exchange:   (half*2+col) regions x 2048 words         = 8192 words
//   epilogue strips:   2 cols x 128 lanes-pair x 33 words stride = 8448 words
#define LS_WORDS 8448

__global__ __launch_bounds__(512, 6) void wass_kernel(const float* __restrict__ pred,
                                                      const float* __restrict__ obs,
                                                      float* __restrict__ out) {
    __shared__ __align__(16) float ls[LS_WORDS];

    const int bid  = blockIdx.x;
    const int cb   = (bid & 7) * 256 + (bid >> 3);   // XCD-band col-block swizzle
    const int col0 = cb * 2;

    const int t    = threadIdx.x;
    const int half = t >> 8;           // 0 = pred, 1 = obs
    const int ht   = t & 255;          // thread within half
    const int wh   = ht >> 6;          // wave within half: 0..3
    const int w2   = wh >> 1;          // column (0..1) this wave-pair sorts
    const int wp   = wh & 1;           // which wave of the pair
    const int L    = t & 63;           // lane
    const int P    = wp * 64 + L;      // 0..127: position of this lane in the pair

    const float* __restrict__ src = half ? obs : pred;

    // ---- staged load + transpose: 2 chunks of 2048 rows ----
    // local row lr = (r>>5)*16 + (r&15); chunk q holds rows with bit4(r)==q,
    // i.e. e in [16q,16q+16) for every P. LDS word = (lr&~31) | ((lr&31)^((lr>>5)&15)):
    // writer and reader both land at <=2-way bank aliasing (free).
    float x[EPT];
    {
        float* stg = ls + half * 4096;
        const int b_w = ht >> 1;           // row-block (0..127) this thread loads
        const int lo  = ht & 1;
        #pragma unroll
        for (int q = 0; q < 2; ++q) {
            #pragma unroll
            for (int k = 0; k < 8; ++k) {
                const int lr = b_w * 16 + lo * 8 + k;
                const int r  = b_w * 32 + q * 16 + lo * 8 + k;
                const float2 v = *(const float2*)&src[(size_t)r * NCOL + col0];
                const int w_ = (lr & ~31) | ((lr & 31) ^ ((lr >> 5) & 15));
                stg[w_]        = v.x;      // column col0
                stg[w_ + 2048] = v.y;      // column col0+1
            }
            __syncthreads();
            #pragma unroll
            for (int s = 0; s < 16; ++s) {
                const int lr = P * 16 + s;
                const int w_ = (lr & ~31) | ((lr & 31) ^ ((lr >> 5) & 15));
                x[q * 16 + s] = stg[w2 * 2048 + w_];
            }
            __syncthreads();
        }
    }

    // ---- phase 1: normalized bitonic sort of my 32 contiguous elements ----
    #pragma unroll
    for (int k = 2; k <= EPT; k <<= 1) {
        #pragma unroll
        for (int base = 0; base < EPT; base += k) {
            #pragma unroll
            for (int o = 0; o < k / 2; ++o)
                cemin(x[base + o], x[base + k - 1 - o]);
        }
        #pragma unroll
        for (int j = k / 4; j >= 1; j >>= 1) {
            #pragma unroll
            for (int e = 0; e < EPT; ++e)
                if ((e & j) == 0) cemin(x[e], x[e | j]);
        }
    }

    // ---- phase 2: merges k = 64..2048, all in-wave, no barriers ----
    cross_merge<2>(x, L);
    cross_merge<4>(x, L);
    cross_merge<8>(x, L);
    cross_merge<16>(x, L);
    cross_merge<32>(x, L);
    cross_merge<64>(x, L);

    // ---- phase 3: k = 4096 merge across the wave pair ----
    // Reversal pairs (P,e) <-> (127-P, 31-e). wp0 parks its 2048 in LDS; wp1
    // reads the mirror, keeps max, writes min back into the same slot; wp0
    // reads back its slots (now the mins). Then plain stages are in-wave again.
    // Slot for (wp0 lane l, elem e): l*32 + (e ^ (l&31))  -> 2-way banks (free).
    {
        float* xb = ls + (half * 2 + w2) * 2048;
        __syncthreads();                   // staging region is dead; safe to reuse
        if (wp == 0) {
            #pragma unroll
            for (int e = 0; e < EPT; ++e)
                xb[(L * 32) | (e ^ (L & 31))] = x[e];
        }
        __syncthreads();
        if (wp == 1) {
            const int Lp = 63 - L;
            #pragma unroll
            for (int e = 0; e < EPT; ++e) {
                const int w_ = (Lp * 32) | ((31 - e) ^ (Lp & 31));
                const float y  = xb[w_];
                const float mn = fminf(x[e], y);
                x[e] = fmaxf(x[e], y);     // upper half keeps max
                xb[w_] = mn;               // lower half's new value, in place
            }
        }
        __syncthreads();
        if (wp == 0) {
            #pragma unroll
            for (int e = 0; e < EPT; ++e)
                x[e] = xb[(L * 32) | (e ^ (L & 31))];
        }
        plains_down<32>(x, L);             // element distances 1024..32
        tail16(x);                         // 16..1
    }

    // ---- epilogue: pred waves park sorted columns in LDS strips (stride 33
    // words -> 2-way banks, free), obs waves diff + reduce ----
    __syncthreads();                       // exchange region is dead
    const int sb = (w2 * 128 + P) * 33;
    if (half == 0) {
        #pragma unroll
        for (int e = 0; e < EPT; ++e)
            ls[sb + e] = x[e];
    }
    __syncthreads();
    if (half == 1) {
        float s = 0.0f;
        #pragma unroll
        for (int e = 0; e < EPT; ++e)
            s += fabsf(x[e] - ls[sb + e]);
        #pragma unroll
        for (int off = 32; off > 0; off >>= 1)
            s += __shfl_down(s, off, 64);
        if (L == 0)
            atomicAdd(out, s * (1.0f / ((float)NT * (float)NCOL)));
    }
}

extern "C" void kernel_launch(void* const* d_in, const int* in_sizes, int n_in,
                              void* d_out, int out_size, void* d_ws, size_t ws_size,
                              hipStream_t stream) {
    const float* pred = (const float*)d_in[0];
    const float* obs  = (const float*)d_in[1];
    float* out = (float*)d_out;
    hipMemsetAsync(out, 0, sizeof(float), stream);
    wass_kernel<<<NBLOCKS, BLOCK, 0, stream>>>(pred, obs, out);
}

// Round 2
// 285.959 us; speedup vs baseline: 1.0079x; 1.0079x over previous
//
#include <hip/hip_runtime.h>

#define NT 4096          // time samples per column
#define NCOL 4096        // 512 traces * 8 channels
#define EPT 64           // elements per lane: one wave sorts one whole column
#define BLOCK 512        // 8 waves: waves 0-3 pred cols w, waves 4-7 obs cols w
#define NBLOCKS 1024     // 4096 cols / 4 cols per block

__device__ __forceinline__ float b2f(int i) { return __builtin_bit_cast(float, i); }
__device__ __forceinline__ int   f2b(float f) { return __builtin_bit_cast(int, f); }

// Cross-lane fetch of partner lane^XM's value.
// XM 1,2,3 (quad_perm), 7 (row_half_mirror), 8 (row_ror:8), 15 (row_mirror): DPP,
// VALU pipe, zero DS traffic. XM 4,16,31: ds_swizzle. XM 63: ds_bpermute.
template <int XM>
__device__ __forceinline__ float lx(float v) {
    const int i = f2b(v);
    int r;
    if constexpr (XM == 1)       r = __builtin_amdgcn_update_dpp(0, i, 0xB1,  0xF, 0xF, true);
    else if constexpr (XM == 2)  r = __builtin_amdgcn_update_dpp(0, i, 0x4E,  0xF, 0xF, true);
    else if constexpr (XM == 3)  r = __builtin_amdgcn_update_dpp(0, i, 0x1B,  0xF, 0xF, true);
    else if constexpr (XM == 7)  r = __builtin_amdgcn_update_dpp(0, i, 0x141, 0xF, 0xF, true);
    else if constexpr (XM == 8)  r = __builtin_amdgcn_update_dpp(0, i, 0x128, 0xF, 0xF, true);
    else if constexpr (XM == 15) r = __builtin_amdgcn_update_dpp(0, i, 0x140, 0xF, 0xF, true);
    else if constexpr (XM == 4)  r = __builtin_amdgcn_ds_swizzle(i, 0x101F);
    else if constexpr (XM == 16) r = __builtin_amdgcn_ds_swizzle(i, 0x401F);
    else if constexpr (XM == 31) r = __builtin_amdgcn_ds_swizzle(i, 0x7C1F);
    else {
        const int lane = (int)(threadIdx.x & 63);
        r = __builtin_amdgcn_ds_bpermute((lane ^ XM) << 2, i);
    }
    return b2f(r);
}

__device__ __forceinline__ void cemin(float& a, float& b) {
    const float lo = fminf(a, b);
    const float hi = fmaxf(a, b);
    a = lo; b = hi;
}
__device__ __forceinline__ float csel(float x, float y, bool keep_min) {
    return ((x < y) == keep_min) ? x : y;
}

// plain cross-lane stage, lane-xor M, same element index
template <int M>
__device__ __forceinline__ void plain_stage(float (&x)[EPT], int L) {
    const bool km = (L & M) == 0;
    #pragma unroll
    for (int e = 0; e < EPT; ++e) {
        const float y = lx<M>(x[e]);
        x[e] = csel(x[e], y, km);
    }
}

template <int M>
__device__ __forceinline__ void plains_down(float (&x)[EPT], int L) {
    plain_stage<M>(x, L);
    if constexpr (M > 1) plains_down<M / 2>(x, L);
}

// intra-thread plain stages j = 32..1, all ascending (normalized network)
__device__ __forceinline__ void tail32(float (&x)[EPT]) {
    #pragma unroll
    for (int j = 32; j >= 1; j >>= 1) {
        #pragma unroll
        for (int e = 0; e < EPT; ++e)
            if ((e & j) == 0) cemin(x[e], x[e | j]);
    }
}

// Normalized bitonic merge of size k = 64*K (K = 2..64), fully in-wave:
// reversal: partner lane L^(K-1), element mirror e<->63-e, keep-min if (L&K/2)==0;
// then plain lane-xor stages m=K/4..1; then intra-thread tail j=32..1.
template <int K>
__device__ __forceinline__ void cross_merge(float (&x)[EPT], int L) {
    const bool km = (L & (K >> 1)) == 0;
    #pragma unroll
    for (int e = 0; e < EPT / 2; ++e) {
        const float ylo = lx<K - 1>(x[EPT - 1 - e]);   // partner's mirrored element
        const float yhi = lx<K - 1>(x[e]);
        x[e]           = csel(x[e], ylo, km);
        x[EPT - 1 - e] = csel(x[EPT - 1 - e], yhi, km);
    }
    if constexpr (K >= 4) plains_down<K / 4>(x, L);
    tail32(x);
}

// LDS: staging transpose (2 halves x 4096 words = 32 KB) unioned with
// epilogue strips (4 cols x 64 lanes x 34 words = 34.8 KB, two 32-elem passes)
#define LS_WORDS 8704

__global__ __launch_bounds__(512, 3) void wass_kernel(const float* __restrict__ pred,
                                                      const float* __restrict__ obs,
                                                      float* __restrict__ out) {
    __shared__ __align__(16) float ls[LS_WORDS];

    const int bid  = blockIdx.x;
    const int cb   = (bid & 7) * 128 + (bid >> 3);   // XCD-band col-block swizzle
    const int col0 = cb * 4;

    const int t    = threadIdx.x;
    const int half = t >> 8;           // 0 = pred, 1 = obs
    const int ht   = t & 255;          // thread within half
    const int w    = (t >> 6) & 3;     // column (0..3) this wave sorts
    const int L    = t & 63;           // lane

    const float* __restrict__ src = half ? obs : pred;
    float* stage = ls + half * 4096;   // 16 KB staging per half

    // ---- staged load + transpose: 4 chunks of 1024 rows ----
    // chunk q holds rows r with ((r>>4)&3)==q, i.e. e in [16q,16q+16) for every lane.
    // staging slot word(b,s,w) = b*64 + 4*(s^(b&15)) + ((w+(b>>4))&3):
    // reader (lane L=b) banks are exactly 2-way aliased = free.
    float x[EPT];
    const int b_w = ht >> 2;           // writer's lane-slot b (0..63)
    const int s4  = ht & 3;            // writer's s-quad
    #pragma unroll
    for (int q = 0; q < 4; ++q) {
        #pragma unroll
        for (int k = 0; k < 4; ++k) {
            const int s = s4 * 4 + k;                      // 0..15 within chunk
            const int r = b_w * 64 + q * 16 + s;           // global row
            const float4 v = *(const float4*)&src[(size_t)r * NCOL + col0];
            const int base = b_w * 64 + 4 * (s ^ (b_w & 15));
            const int ro   = b_w >> 4;
            stage[base + (( ro    ) & 3)] = v.x;
            stage[base + ((1 + ro) & 3)] = v.y;
            stage[base + ((2 + ro) & 3)] = v.z;
            stage[base + ((3 + ro) & 3)] = v.w;
        }
        __syncthreads();
        #pragma unroll
        for (int s = 0; s < 16; ++s) {
            const int word = L * 64 + 4 * (s ^ (L & 15)) + ((w + (L >> 4)) & 3);
            x[q * 16 + s] = stage[word];
        }
        __syncthreads();
    }

    // ---- phase 1: normalized bitonic sort of my 64 contiguous elements ----
    #pragma unroll
    for (int k = 2; k <= 64; k <<= 1) {
        #pragma unroll
        for (int base = 0; base < EPT; base += k) {
            #pragma unroll
            for (int o = 0; o < k / 2; ++o)
                cemin(x[base + o], x[base + k - 1 - o]);
        }
        #pragma unroll
        for (int j = k / 4; j >= 1; j >>= 1) {
            #pragma unroll
            for (int e = 0; e < EPT; ++e)
                if ((e & j) == 0) cemin(x[e], x[e | j]);
        }
    }

    // ---- phase 2: merges k = 128..4096, all in-wave, no barriers ----
    cross_merge<2>(x, L);
    cross_merge<4>(x, L);
    cross_merge<8>(x, L);
    cross_merge<16>(x, L);
    cross_merge<32>(x, L);
    cross_merge<64>(x, L);

    // ---- epilogue: two 32-element passes. pred waves park half a sorted
    // column in LDS strips (stride 34 words -> b64 pair-groups 2-way = free),
    // obs waves diff + accumulate. Halves the strip LDS vs one-shot. ----
    __syncthreads();                   // staging region is dead; safe to reuse
    const int sb = (w * 64 + L) * 34;
    float s = 0.0f;
    #pragma unroll
    for (int hh = 0; hh < 2; ++hh) {
        if (half == 0) {
            #pragma unroll
            for (int q = 0; q < 16; ++q)
                *(float2*)&ls[sb + 2 * q] =
                    make_float2(x[hh * 32 + 2 * q], x[hh * 32 + 2 * q + 1]);
        }
        __syncthreads();
        if (half == 1) {
            #pragma unroll
            for (int q = 0; q < 16; ++q) {
                const float2 p = *(const float2*)&ls[sb + 2 * q];
                s += fabsf(x[hh * 32 + 2 * q] - p.x) +
                     fabsf(x[hh * 32 + 2 * q + 1] - p.y);
            }
        }
        __syncthreads();
    }
    if (half == 1) {
        #pragma unroll
        for (int off = 32; off > 0; off >>= 1)
            s += __shfl_down(s, off, 64);
        if (L == 0)
            atomicAdd(out, s * (1.0f / ((float)NT * (float)NCOL)));
    }
}

extern "C" void kernel_launch(void* const* d_in, const int* in_sizes, int n_in,
                              void* d_out, int out_size, void* d_ws, size_t ws_size,
                              hipStream_t stream) {
    const float* pred = (const float*)d_in[0];
    const float* obs  = (const float*)d_in[1];
    float* out = (float*)d_out;
    hipMemsetAsync(out, 0, sizeof(float), stream);
    wass_kernel<<<NBLOCKS, BLOCK, 0, stream>>>(pred, obs, out);
}